// Round 4
// baseline (10604.726 us; speedup 1.0000x reference)
//
#include <hip/hip_runtime.h>

// Chemprop BondMessagePassing, DEPTH=3, eval mode.
// R3 baseline (9.6 ms) was latency-bound: VALUBusy 20%, HBM 11%, occupancy 22%
// — per-chunk gather loads (x[src]/S[src]) fully exposed between two barriers.
// R4: double-buffered At/Wt + register prefetch; one barrier per chunk; the
// chunk c+1 gather is issued right after the barrier and consumed one
// iteration later, hidden behind ~1280 cy of FMA issue.
// ws usage stays 64 MB: S0|S2 in ws, S1 in d_out. H never materialized;
// H[rev] is tile-local (pairs (2i,2i+1), TE=64 even) via LDS Hbuf.

#define E_EDGES 500000
#define N_NODES 50000
#define HD      160     // HIDDEN == NODE_DIM
#define BD      14      // BOND_DIM
#define K1      174     // NODE_DIM + BOND_DIM
#define K1P     176     // padded to KC multiple
#define KO      320     // NODE_DIM + HIDDEN

#define TE 64           // edge/node rows per block
#define KC 16           // k-chunk staged in LDS
#define NC1 (K1P / KC)  // 11 chunks, phase 1
#define NC2 (HD / KC)   // 10 chunks, phase 2+

// ---------------------------------------------------------------------------
__global__ void k_zero(float* __restrict__ p, long n)
{
    const long i = (long)blockIdx.x * 1024 + (long)threadIdx.x * 4;
    if (i + 3 < n) *(float4*)(p + i) = make_float4(0.f, 0.f, 0.f, 0.f);
}

// ---------------------------------------------------------------------------
__device__ __forceinline__
void gemm_chunk(float acc[4][10], const float At[KC][TE + 4],
                const float Wt[KC][HD + 8], int tr, int tc)
{
    #pragma unroll
    for (int k = 0; k < KC; ++k) {
        const float4 a  = *(const float4*)&At[k][tr * 4];
        const float* wp = &Wt[k][tc * 10];
        float w[10];
        #pragma unroll
        for (int j = 0; j < 10; j += 2) {
            const float2 w2 = *(const float2*)(wp + j);
            w[j] = w2.x; w[j + 1] = w2.y;
        }
        #pragma unroll
        for (int j = 0; j < 10; ++j) {
            acc[0][j] = fmaf(a.x, w[j], acc[0][j]);
            acc[1][j] = fmaf(a.y, w[j], acc[1][j]);
            acc[2][j] = fmaf(a.z, w[j], acc[2][j]);
            acc[3][j] = fmaf(a.w, w[j], acc[3][j]);
        }
    }
}

// ---------------------------------------------------------------------------
// k_mp<LAYERS>: per 64-edge tile, recompute H0 (>=1), H1 (>=2, needs S0),
// H2 (>=3, needs S1); scatter-add last layer into Sout[dst[e]].
// Block 256 = 16(e) x 16(h); thread tile 4 rows x 10 cols.
// Pipeline invariant: one __syncthreads per chunk; write LDS[buf] -> barrier
// -> prefetch c+1 -> compute LDS[buf]. Buf parity resets to 0 each phase;
// the phase-boundary barrier separates the old buf0 readers from new writers.
// ---------------------------------------------------------------------------
template <int LAYERS>
__global__ __launch_bounds__(256, (LAYERS == 1) ? 4 : 2)
void k_mp(const float* __restrict__ x, const float* __restrict__ ea,
          const int* __restrict__ src, const int* __restrict__ dst,
          const float* __restrict__ Wi, const float* __restrict__ bi,
          const float* __restrict__ Wh, const float* __restrict__ bh,
          const float* __restrict__ S0, const float* __restrict__ S1,
          float* __restrict__ Sout)
{
    __shared__ float At[2][KC][TE + 4];                    //  8.7 KB
    __shared__ float Wt[2][KC][HD + 8];                    // 21.5 KB
    __shared__ float Hbuf[(LAYERS >= 2) ? TE : 1][HD + 4]; // 42 KB (L>=2)

    const int  t    = threadIdx.x;
    const long base = (long)blockIdx.x * TE;

    // staging ids: thread t handles float4 slot (t&3) of tile row (t>>2)
    const int  se   = t >> 2;
    const int  skq  = t & 3;
    const long ge   = base + se;
    const bool ev   = ge < E_EDGES;
    const long gec  = ev ? ge : 0;
    const int  sidx = ev ? src[ge] : 0;
    const float* xrow = x  + (long)sidx * HD;
    const float* erow = ea + gec * BD;

    // weight staging ids: kk = t&15 (fixed), h = (t>>4) + 16m, m = 0..9
    const int wk  = t & 15;
    const int wh0 = t >> 4;

    // compute ids
    const int tr = t >> 4;
    const int tc = t & 15;

    float4 pa;        // prefetched A slice
    float  pw[10];    // prefetched W slice

    float acc[4][10];
    #pragma unroll
    for (int i = 0; i < 4; ++i)
        #pragma unroll
        for (int j = 0; j < 10; ++j) acc[i][j] = 0.f;

    // ---- phase 1: acc = [x[src]; ea] @ Wi^T ----
    auto pf_a1 = [&](int c) {
        const int kb = c * KC + skq * 4;
        if (kb + 3 < HD) {
            pa = *(const float4*)(xrow + kb);
        } else {
            float tmp[4];
            #pragma unroll
            for (int j = 0; j < 4; ++j) {
                const int k = kb + j;
                tmp[j] = (k < HD) ? xrow[k] : ((k < K1) ? erow[k - HD] : 0.f);
            }
            pa = make_float4(tmp[0], tmp[1], tmp[2], tmp[3]);
        }
    };
    auto pf_w = [&](const float* __restrict__ W, int ld, int kmax, int c) {
        const int k = c * KC + wk;
        #pragma unroll
        for (int m = 0; m < 10; ++m)
            pw[m] = (k < kmax) ? W[(wh0 + 16 * m) * ld + k] : 0.f;
    };

    pf_a1(0);
    pf_w(Wi, K1, K1, 0);
    for (int c = 0; c < NC1; ++c) {
        const int buf = c & 1;
        At[buf][skq * 4 + 0][se] = pa.x;
        At[buf][skq * 4 + 1][se] = pa.y;
        At[buf][skq * 4 + 2][se] = pa.z;
        At[buf][skq * 4 + 3][se] = pa.w;
        #pragma unroll
        for (int m = 0; m < 10; ++m) Wt[buf][wk][wh0 + 16 * m] = pw[m];
        __syncthreads();
        if (c + 1 < NC1) { pf_a1(c + 1); pf_w(Wi, K1, K1, c + 1); }
        gemm_chunk(acc, At[buf], Wt[buf], tr, tc);
    }
    // acc = H0 = relu(acc + bi)
    #pragma unroll
    for (int j = 0; j < 10; ++j) {
        const float b = bi[tc * 10 + j];
        #pragma unroll
        for (int i = 0; i < 4; ++i) {
            const float v = acc[i][j] + b;
            acc[i][j] = v > 0.f ? v : 0.f;
        }
    }

    float h0r[4][10];
    if (LAYERS >= 2) {
        // save H0 and publish the tile to Hbuf
        #pragma unroll
        for (int i = 0; i < 4; ++i)
            #pragma unroll
            for (int j = 0; j < 10; ++j) h0r[i][j] = acc[i][j];
        #pragma unroll
        for (int i = 0; i < 4; ++i)
            #pragma unroll
            for (int j = 0; j < 10; j += 2)
                *(float2*)&Hbuf[tr * 4 + i][tc * 10 + j] =
                    make_float2(acc[i][j], acc[i][j + 1]);
        __syncthreads();   // Hbuf visible; also separates phase-1 buf0 readers

        #pragma unroll
        for (int l = 1; l < LAYERS; ++l) {
            const float* Sp   = (l == 1) ? S0 : S1;
            const float* mrow = Sp + (long)sidx * HD;
            #pragma unroll
            for (int i = 0; i < 4; ++i)
                #pragma unroll
                for (int j = 0; j < 10; ++j) acc[i][j] = 0.f;

            pa = *(const float4*)(mrow + skq * 4);
            pf_w(Wh, HD, HD, 0);
            for (int c = 0; c < NC2; ++c) {
                const int buf = c & 1;
                const int kb  = c * KC + skq * 4;
                {   // At = M[src] - H_prev[rev]; rev row is se^1 (tile-local)
                    const float4 r = *(const float4*)&Hbuf[se ^ 1][kb];
                    At[buf][skq * 4 + 0][se] = pa.x - r.x;
                    At[buf][skq * 4 + 1][se] = pa.y - r.y;
                    At[buf][skq * 4 + 2][se] = pa.z - r.z;
                    At[buf][skq * 4 + 3][se] = pa.w - r.w;
                }
                #pragma unroll
                for (int m = 0; m < 10; ++m) Wt[buf][wk][wh0 + 16 * m] = pw[m];
                __syncthreads();
                if (c + 1 < NC2) {
                    pa = *(const float4*)(mrow + (c + 1) * KC + skq * 4);
                    pf_w(Wh, HD, HD, c + 1);
                }
                gemm_chunk(acc, At[buf], Wt[buf], tr, tc);
            }
            // acc = relu(H0 + acc + bh)
            #pragma unroll
            for (int j = 0; j < 10; ++j) {
                const float b = bh[tc * 10 + j];
                #pragma unroll
                for (int i = 0; i < 4; ++i) {
                    const float v = h0r[i][j] + acc[i][j] + b;
                    acc[i][j] = v > 0.f ? v : 0.f;
                }
            }
            if (l < LAYERS - 1) {
                // republish H tile (old-Hbuf reads all ended before the last
                // pre-compute barrier of this layer)
                #pragma unroll
                for (int i = 0; i < 4; ++i)
                    #pragma unroll
                    for (int j = 0; j < 10; j += 2)
                        *(float2*)&Hbuf[tr * 4 + i][tc * 10 + j] =
                            make_float2(acc[i][j], acc[i][j + 1]);
                __syncthreads();   // new Hbuf visible before next layer's writes
            }
        }
    }

    // ---- epilogue: scatter-add last layer into Sout[dst[e]] ----
    #pragma unroll
    for (int i = 0; i < 4; ++i) {
        const long e = base + tr * 4 + i;
        if (e >= E_EDGES) break;
        const int  de = dst[e];
        float* mp = Sout + (long)de * HD + tc * 10;
        #pragma unroll
        for (int j = 0; j < 10; ++j)
            unsafeAtomicAdd(mp + j, acc[i][j]);
    }
}

// ---------------------------------------------------------------------------
// k_mfix: if sum(Mg[n]) == 0, replace row with x[n]. One wave per node.
// ---------------------------------------------------------------------------
__global__ void k_mfix(float* __restrict__ Mg, const float* __restrict__ x)
{
    const int  lane = threadIdx.x & 63;
    const int  w    = threadIdx.x >> 6;
    const long n    = (long)blockIdx.x * 4 + w;
    if (n >= N_NODES) return;
    const long b = n * HD;
    float s = Mg[b + lane] + Mg[b + 64 + lane] + ((lane < 32) ? Mg[b + 128 + lane] : 0.f);
    #pragma unroll
    for (int off = 32; off > 0; off >>= 1) s += __shfl_xor(s, off, 64);
    if (s == 0.f) {
        Mg[b + lane]      = x[b + lane];
        Mg[b + 64 + lane] = x[b + 64 + lane];
        if (lane < 32) Mg[b + 128 + lane] = x[b + 128 + lane];
    }
}

// ---------------------------------------------------------------------------
// k_out: out[n] = relu(Wo @ [x[n]; M[n]] + bo)
// ---------------------------------------------------------------------------
__global__ __launch_bounds__(256, 2)
void k_out(const float* __restrict__ x, const float* __restrict__ Mg,
           const float* __restrict__ Wo, const float* __restrict__ bo,
           float* __restrict__ out)
{
    __shared__ float At[KC][TE + 4];
    __shared__ float Wt[KC][HD + 8];

    const int  t    = threadIdx.x;
    const long base = (long)blockIdx.x * TE;

    const int  se  = t >> 2;
    const int  skq = t & 3;
    const long gn  = base + se;
    const bool ev  = gn < N_NODES;
    const long gnc = ev ? gn : 0;
    const float* xrow = x  + gnc * HD;
    const float* mrow = Mg + gnc * HD;

    const int tr = t >> 4;
    const int tc = t & 15;

    float acc[4][10];
    #pragma unroll
    for (int i = 0; i < 4; ++i)
        #pragma unroll
        for (int j = 0; j < 10; ++j) acc[i][j] = 0.f;

    for (int c = 0; c < KO / KC; ++c) {   // 20 chunks: 0-9 from x, 10-19 from M
        const int k0 = c * KC;
        __syncthreads();
        {
            const int kb = k0 + skq * 4;
            const float4 v = (kb < HD) ? *(const float4*)(xrow + kb)
                                       : *(const float4*)(mrow + (kb - HD));
            At[skq * 4 + 0][se] = v.x;
            At[skq * 4 + 1][se] = v.y;
            At[skq * 4 + 2][se] = v.z;
            At[skq * 4 + 3][se] = v.w;
        }
        for (int i = t; i < HD * KC; i += 256) {
            const int kk = i & (KC - 1);
            const int h  = i >> 4;
            Wt[kk][h] = Wo[h * KO + k0 + kk];
        }
        __syncthreads();
        gemm_chunk(acc, At, Wt, tr, tc);
    }
    #pragma unroll
    for (int i = 0; i < 4; ++i) {
        const long n = base + tr * 4 + i;
        if (n >= N_NODES) break;
        float* op = out + n * HD + tc * 10;
        #pragma unroll
        for (int j = 0; j < 10; j += 2) {
            float v0 = acc[i][j]     + bo[tc * 10 + j];
            float v1 = acc[i][j + 1] + bo[tc * 10 + j + 1];
            v0 = v0 > 0.f ? v0 : 0.f;
            v1 = v1 > 0.f ? v1 : 0.f;
            *(float2*)(op + j) = make_float2(v0, v1);
        }
    }
}

// ---------------------------------------------------------------------------
extern "C" void kernel_launch(void* const* d_in, const int* in_sizes, int n_in,
                              void* d_out, int out_size, void* d_ws, size_t ws_size,
                              hipStream_t stream)
{
    const float* x  = (const float*)d_in[0];
    const float* ea = (const float*)d_in[1];
    const int*   ei = (const int*)d_in[2];
    // d_in[3] = rev_edge_index: structurally e^1, handled tile-locally.
    const float* Wi = (const float*)d_in[4];
    const float* bi = (const float*)d_in[5];
    const float* Wh = (const float*)d_in[6];
    const float* bh = (const float*)d_in[7];
    const float* Wo = (const float*)d_in[8];
    const float* bo = (const float*)d_in[9];
    float* out = (float*)d_out;

    const int* src = ei;             // edge_index[0]
    const int* dst = ei + E_EDGES;   // edge_index[1]

    const long NM = (long)N_NODES * HD;          // 8,000,000 floats = 32 MB
    float* S0 = (float*)d_ws;                    // ws[0   .. 32MB)
    float* S2 = S0 + NM;                         // ws[32MB.. 64MB)
    float* S1 = out;                             // d_out doubles as S1 scratch

    const int gE = (E_EDGES + TE - 1) / TE;      // 7813
    const int gN = (N_NODES + TE - 1) / TE;      // 782
    const int gF = (N_NODES + 3) / 4;            // 12500
    const int gZ2 = (int)((2 * NM + 1023) / 1024);
    const int gZ1 = (int)((NM + 1023) / 1024);

    k_zero<<<gZ2, 256, 0, stream>>>(S0, 2 * NM);     // S0 and S2
    k_zero<<<gZ1, 256, 0, stream>>>(S1, NM);

    k_mp<1><<<gE, 256, 0, stream>>>(x, ea, src, dst, Wi, bi, Wh, bh, x, x, S0);
    k_mp<2><<<gE, 256, 0, stream>>>(x, ea, src, dst, Wi, bi, Wh, bh, S0, S0, S1);
    k_mp<3><<<gE, 256, 0, stream>>>(x, ea, src, dst, Wi, bi, Wh, bh, S0, S1, S2);

    k_mfix<<<gF, 256, 0, stream>>>(S2, x);
    k_out<<<gN, 256, 0, stream>>>(x, S2, Wo, bo, out);
}

// Round 5
// 9124.495 us; speedup vs baseline: 1.1622x; 1.1622x over previous
//
#include <hip/hip_runtime.h>

// Chemprop BondMessagePassing, DEPTH=3, eval mode.
// R4 post-mortem: k_mp<1> is scatter-atomic-bound (80M random fp32 atomics into
// 32MB -> L2 RMW thrash; 15GB HBM traffic at occ=4). The pipeline helped the
// GEMM-heavy kernels. R5: two paths, chosen by ws_size (deterministic, capture
// safe):
//  FAT (ws >= 675MB): materialize H0/H, CSR(dst) built per call, segment-sum
//    as per-node GATHER (zero atomics), pipelined edge-tile update GEMM with
//    in-place H (rev=e^1 is tile-local; reads precede last barrier).
//  SLIM (fallback): R4 structure, k_mp<1> restored to (256,2).

#define E_EDGES 500000
#define N_NODES 50000
#define HD      160
#define BD      14
#define K1      174
#define K1P     176
#define KO      320

#define TE 64
#define KC 16
#define NC1 (K1P / KC)  // 11
#define NC2 (HD / KC)   // 10

// ---------------------------------------------------------------------------
__global__ void k_zero(float* __restrict__ p, long n)
{
    const long i = (long)blockIdx.x * 1024 + (long)threadIdx.x * 4;
    if (i + 3 < n) *(float4*)(p + i) = make_float4(0.f, 0.f, 0.f, 0.f);
}

// ---------------------------------------------------------------------------
__device__ __forceinline__
void gemm_chunk(float acc[4][10], const float At[KC][TE + 4],
                const float Wt[KC][HD + 8], int tr, int tc)
{
    #pragma unroll
    for (int k = 0; k < KC; ++k) {
        const float4 a  = *(const float4*)&At[k][tr * 4];
        const float* wp = &Wt[k][tc * 10];
        float w[10];
        #pragma unroll
        for (int j = 0; j < 10; j += 2) {
            const float2 w2 = *(const float2*)(wp + j);
            w[j] = w2.x; w[j + 1] = w2.y;
        }
        #pragma unroll
        for (int j = 0; j < 10; ++j) {
            acc[0][j] = fmaf(a.x, w[j], acc[0][j]);
            acc[1][j] = fmaf(a.y, w[j], acc[1][j]);
            acc[2][j] = fmaf(a.z, w[j], acc[2][j]);
            acc[3][j] = fmaf(a.w, w[j], acc[3][j]);
        }
    }
}

// ============================ FAT PATH =====================================

// ---- CSR build ----
__global__ void k_csr_count(const int* __restrict__ dst, int* __restrict__ cnt)
{
    const int e = blockIdx.x * 256 + threadIdx.x;
    if (e < E_EDGES) atomicAdd(&cnt[dst[e]], 1);
}

// one block, 1024 threads: exclusive prefix over 50000 bins -> ptr[50001]
#define BPT 49
__global__ __launch_bounds__(1024)
void k_csr_scan(const int* __restrict__ cnt, int* __restrict__ ptr)
{
    __shared__ int part[1024];
    const int t  = threadIdx.x;
    const int lo = t * BPT;
    const int hi = min(lo + BPT, N_NODES);
    int s = 0;
    for (int i = lo; i < hi; ++i) s += cnt[i];
    part[t] = s;
    __syncthreads();
    for (int off = 1; off < 1024; off <<= 1) {
        int v = 0;
        if (t >= off) v = part[t - off];
        __syncthreads();
        if (t >= off) part[t] += v;
        __syncthreads();
    }
    int run = (t == 0) ? 0 : part[t - 1];
    for (int i = lo; i < hi; ++i) { ptr[i] = run; run += cnt[i]; }
    if (t == 1023) ptr[N_NODES] = part[1023];
}

__global__ void k_csr_fill(const int* __restrict__ dst, const int* __restrict__ ptr,
                           int* __restrict__ cur, int* __restrict__ eid)
{
    const int e = blockIdx.x * 256 + threadIdx.x;
    if (e < E_EDGES) {
        const int d   = dst[e];
        const int pos = atomicAdd(&cur[d], 1);
        eid[ptr[d] + pos] = e;
    }
}

// ---- k_h0f: H0 = relu(Wi @ [x[src]; ea] + bi); H = H0. Sequential writes. --
__global__ __launch_bounds__(256, 4)
void k_h0f(const float* __restrict__ x, const float* __restrict__ ea,
           const int* __restrict__ src,
           const float* __restrict__ Wi, const float* __restrict__ bi,
           float* __restrict__ H0, float* __restrict__ H)
{
    __shared__ float At[2][KC][TE + 4];
    __shared__ float Wt[2][KC][HD + 8];

    const int  t    = threadIdx.x;
    const long base = (long)blockIdx.x * TE;
    const int  se   = t >> 2;
    const int  skq  = t & 3;
    const long ge   = base + se;
    const bool ev   = ge < E_EDGES;
    const long gec  = ev ? ge : 0;
    const int  sidx = ev ? src[ge] : 0;
    const float* xrow = x  + (long)sidx * HD;
    const float* erow = ea + gec * BD;
    const int wk = t & 15, wh0 = t >> 4;
    const int tr = t >> 4, tc = t & 15;

    float4 pa; float pw[10];
    float acc[4][10];
    #pragma unroll
    for (int i = 0; i < 4; ++i)
        #pragma unroll
        for (int j = 0; j < 10; ++j) acc[i][j] = 0.f;

    auto pf_a = [&](int c) {
        const int kb = c * KC + skq * 4;
        if (kb + 3 < HD) pa = *(const float4*)(xrow + kb);
        else {
            float tmp[4];
            #pragma unroll
            for (int j = 0; j < 4; ++j) {
                const int k = kb + j;
                tmp[j] = (k < HD) ? xrow[k] : ((k < K1) ? erow[k - HD] : 0.f);
            }
            pa = make_float4(tmp[0], tmp[1], tmp[2], tmp[3]);
        }
    };
    auto pf_w = [&](int c) {
        const int k = c * KC + wk;
        #pragma unroll
        for (int m = 0; m < 10; ++m)
            pw[m] = (k < K1) ? Wi[(wh0 + 16 * m) * K1 + k] : 0.f;
    };

    pf_a(0); pf_w(0);
    for (int c = 0; c < NC1; ++c) {
        const int buf = c & 1;
        At[buf][skq * 4 + 0][se] = pa.x;
        At[buf][skq * 4 + 1][se] = pa.y;
        At[buf][skq * 4 + 2][se] = pa.z;
        At[buf][skq * 4 + 3][se] = pa.w;
        #pragma unroll
        for (int m = 0; m < 10; ++m) Wt[buf][wk][wh0 + 16 * m] = pw[m];
        __syncthreads();
        if (c + 1 < NC1) { pf_a(c + 1); pf_w(c + 1); }
        gemm_chunk(acc, At[buf], Wt[buf], tr, tc);
    }
    #pragma unroll
    for (int i = 0; i < 4; ++i) {
        const long e = base + tr * 4 + i;
        if (e >= E_EDGES) break;
        float* h0p = H0 + e * HD + tc * 10;
        float* hp  = H  + e * HD + tc * 10;
        #pragma unroll
        for (int j = 0; j < 10; j += 2) {
            float v0 = acc[i][j]     + bi[tc * 10 + j];
            float v1 = acc[i][j + 1] + bi[tc * 10 + j + 1];
            v0 = v0 > 0.f ? v0 : 0.f;
            v1 = v1 > 0.f ? v1 : 0.f;
            *(float2*)(h0p + j) = make_float2(v0, v1);
            *(float2*)(hp  + j) = make_float2(v0, v1);
        }
    }
}

// ---- k_seg<FINAL>: S[n] = sum_{e in in(n)} H[e]; FINAL also applies the
// sum==0 -> x fallback. One wave per node, 4 waves/block. Zero atomics. ----
template <bool FINAL>
__global__ void k_seg(const float* __restrict__ H, const int* __restrict__ ptr,
                      const int* __restrict__ eid, const float* __restrict__ x,
                      float* __restrict__ S)
{
    const int  lane = threadIdx.x & 63;
    const int  w    = threadIdx.x >> 6;
    const long n    = (long)blockIdx.x * 4 + w;
    if (n >= N_NODES) return;
    const int p0 = ptr[n], p1 = ptr[n + 1];
    float a0 = 0.f, a1 = 0.f, a2 = 0.f;
    for (int i = p0; i < p1; ++i) {
        const long b = (long)eid[i] * HD;
        a0 += H[b + lane];
        a1 += H[b + 64 + lane];
        if (lane < 32) a2 += H[b + 128 + lane];
    }
    const long sb = n * HD;
    if (FINAL) {
        float s = a0 + a1 + a2;
        #pragma unroll
        for (int off = 32; off > 0; off >>= 1) s += __shfl_xor(s, off, 64);
        if (s == 0.f) {
            S[sb + lane]      = x[sb + lane];
            S[sb + 64 + lane] = x[sb + 64 + lane];
            if (lane < 32) S[sb + 128 + lane] = x[sb + 128 + lane];
            return;
        }
    }
    S[sb + lane]      = a0;
    S[sb + 64 + lane] = a1;
    if (lane < 32) S[sb + 128 + lane] = a2;
}

// ---- k_updf: H[e] = relu(H0[e] + Wh @ (S[src[e]] - H[e^1]) + bh), in place.
// All global-H reads precede the last block barrier; writes follow it. ----
__global__ __launch_bounds__(256, 4)
void k_updf(const float* __restrict__ S, const float* __restrict__ H0,
            const int* __restrict__ src,
            const float* __restrict__ Wh, const float* __restrict__ bh,
            float* __restrict__ H)
{
    __shared__ float At[2][KC][TE + 4];
    __shared__ float Wt[2][KC][HD + 8];

    const int  t    = threadIdx.x;
    const long base = (long)blockIdx.x * TE;
    const int  se   = t >> 2;
    const int  skq  = t & 3;
    const long ge   = base + se;
    const bool ev   = ge < E_EDGES;
    const int  sidx = ev ? src[ge] : 0;
    const float* mrow = S + (long)sidx * HD;
    const float* rrow = H + ((ev ? ge : 0) ^ 1) * HD;
    const int wk = t & 15, wh0 = t >> 4;
    const int tr = t >> 4, tc = t & 15;

    float4 pm, pr; float pw[10];
    float acc[4][10];
    #pragma unroll
    for (int i = 0; i < 4; ++i)
        #pragma unroll
        for (int j = 0; j < 10; ++j) acc[i][j] = 0.f;

    auto pf_w = [&](int c) {
        const int k = c * KC + wk;
        #pragma unroll
        for (int m = 0; m < 10; ++m) pw[m] = Wh[(wh0 + 16 * m) * HD + k];
    };

    pm = *(const float4*)(mrow + skq * 4);
    pr = *(const float4*)(rrow + skq * 4);
    pf_w(0);
    for (int c = 0; c < NC2; ++c) {
        const int buf = c & 1;
        At[buf][skq * 4 + 0][se] = pm.x - pr.x;
        At[buf][skq * 4 + 1][se] = pm.y - pr.y;
        At[buf][skq * 4 + 2][se] = pm.z - pr.z;
        At[buf][skq * 4 + 3][se] = pm.w - pr.w;
        #pragma unroll
        for (int m = 0; m < 10; ++m) Wt[buf][wk][wh0 + 16 * m] = pw[m];
        __syncthreads();
        if (c + 1 < NC2) {
            const int kb = (c + 1) * KC + skq * 4;
            pm = *(const float4*)(mrow + kb);
            pr = *(const float4*)(rrow + kb);
            pf_w(c + 1);
        }
        gemm_chunk(acc, At[buf], Wt[buf], tr, tc);
    }
    #pragma unroll
    for (int i = 0; i < 4; ++i) {
        const long e = base + tr * 4 + i;
        if (e >= E_EDGES) break;
        const float* h0p = H0 + e * HD + tc * 10;
        float*       hp  = H  + e * HD + tc * 10;
        #pragma unroll
        for (int j = 0; j < 10; j += 2) {
            const float2 h0 = *(const float2*)(h0p + j);
            float v0 = acc[i][j]     + h0.x + bh[tc * 10 + j];
            float v1 = acc[i][j + 1] + h0.y + bh[tc * 10 + j + 1];
            v0 = v0 > 0.f ? v0 : 0.f;
            v1 = v1 > 0.f ? v1 : 0.f;
            *(float2*)(hp + j) = make_float2(v0, v1);
        }
    }
}

// ============================ SLIM PATH (R4 fallback) ======================

template <int LAYERS>
__global__ __launch_bounds__(256, 2)
void k_mp(const float* __restrict__ x, const float* __restrict__ ea,
          const int* __restrict__ src, const int* __restrict__ dst,
          const float* __restrict__ Wi, const float* __restrict__ bi,
          const float* __restrict__ Wh, const float* __restrict__ bh,
          const float* __restrict__ S0, const float* __restrict__ S1,
          float* __restrict__ Sout)
{
    __shared__ float At[2][KC][TE + 4];
    __shared__ float Wt[2][KC][HD + 8];
    __shared__ float Hbuf[(LAYERS >= 2) ? TE : 1][HD + 4];

    const int  t    = threadIdx.x;
    const long base = (long)blockIdx.x * TE;
    const int  se   = t >> 2;
    const int  skq  = t & 3;
    const long ge   = base + se;
    const bool ev   = ge < E_EDGES;
    const long gec  = ev ? ge : 0;
    const int  sidx = ev ? src[ge] : 0;
    const float* xrow = x  + (long)sidx * HD;
    const float* erow = ea + gec * BD;
    const int wk = t & 15, wh0 = t >> 4;
    const int tr = t >> 4, tc = t & 15;

    float4 pa; float pw[10];
    float acc[4][10];
    #pragma unroll
    for (int i = 0; i < 4; ++i)
        #pragma unroll
        for (int j = 0; j < 10; ++j) acc[i][j] = 0.f;

    auto pf_a1 = [&](int c) {
        const int kb = c * KC + skq * 4;
        if (kb + 3 < HD) pa = *(const float4*)(xrow + kb);
        else {
            float tmp[4];
            #pragma unroll
            for (int j = 0; j < 4; ++j) {
                const int k = kb + j;
                tmp[j] = (k < HD) ? xrow[k] : ((k < K1) ? erow[k - HD] : 0.f);
            }
            pa = make_float4(tmp[0], tmp[1], tmp[2], tmp[3]);
        }
    };
    auto pf_w = [&](const float* __restrict__ W, int ld, int kmax, int c) {
        const int k = c * KC + wk;
        #pragma unroll
        for (int m = 0; m < 10; ++m)
            pw[m] = (k < kmax) ? W[(wh0 + 16 * m) * ld + k] : 0.f;
    };

    pf_a1(0); pf_w(Wi, K1, K1, 0);
    for (int c = 0; c < NC1; ++c) {
        const int buf = c & 1;
        At[buf][skq * 4 + 0][se] = pa.x;
        At[buf][skq * 4 + 1][se] = pa.y;
        At[buf][skq * 4 + 2][se] = pa.z;
        At[buf][skq * 4 + 3][se] = pa.w;
        #pragma unroll
        for (int m = 0; m < 10; ++m) Wt[buf][wk][wh0 + 16 * m] = pw[m];
        __syncthreads();
        if (c + 1 < NC1) { pf_a1(c + 1); pf_w(Wi, K1, K1, c + 1); }
        gemm_chunk(acc, At[buf], Wt[buf], tr, tc);
    }
    #pragma unroll
    for (int j = 0; j < 10; ++j) {
        const float b = bi[tc * 10 + j];
        #pragma unroll
        for (int i = 0; i < 4; ++i) {
            const float v = acc[i][j] + b;
            acc[i][j] = v > 0.f ? v : 0.f;
        }
    }

    float h0r[4][10];
    if (LAYERS >= 2) {
        #pragma unroll
        for (int i = 0; i < 4; ++i)
            #pragma unroll
            for (int j = 0; j < 10; ++j) h0r[i][j] = acc[i][j];
        #pragma unroll
        for (int i = 0; i < 4; ++i)
            #pragma unroll
            for (int j = 0; j < 10; j += 2)
                *(float2*)&Hbuf[tr * 4 + i][tc * 10 + j] =
                    make_float2(acc[i][j], acc[i][j + 1]);
        __syncthreads();

        #pragma unroll
        for (int l = 1; l < LAYERS; ++l) {
            const float* Sp   = (l == 1) ? S0 : S1;
            const float* mrow = Sp + (long)sidx * HD;
            #pragma unroll
            for (int i = 0; i < 4; ++i)
                #pragma unroll
                for (int j = 0; j < 10; ++j) acc[i][j] = 0.f;

            pa = *(const float4*)(mrow + skq * 4);
            pf_w(Wh, HD, HD, 0);
            for (int c = 0; c < NC2; ++c) {
                const int buf = c & 1;
                const int kb  = c * KC + skq * 4;
                {
                    const float4 r = *(const float4*)&Hbuf[se ^ 1][kb];
                    At[buf][skq * 4 + 0][se] = pa.x - r.x;
                    At[buf][skq * 4 + 1][se] = pa.y - r.y;
                    At[buf][skq * 4 + 2][se] = pa.z - r.z;
                    At[buf][skq * 4 + 3][se] = pa.w - r.w;
                }
                #pragma unroll
                for (int m = 0; m < 10; ++m) Wt[buf][wk][wh0 + 16 * m] = pw[m];
                __syncthreads();
                if (c + 1 < NC2) {
                    pa = *(const float4*)(mrow + (c + 1) * KC + skq * 4);
                    pf_w(Wh, HD, HD, c + 1);
                }
                gemm_chunk(acc, At[buf], Wt[buf], tr, tc);
            }
            #pragma unroll
            for (int j = 0; j < 10; ++j) {
                const float b = bh[tc * 10 + j];
                #pragma unroll
                for (int i = 0; i < 4; ++i) {
                    const float v = h0r[i][j] + acc[i][j] + b;
                    acc[i][j] = v > 0.f ? v : 0.f;
                }
            }
            if (l < LAYERS - 1) {
                #pragma unroll
                for (int i = 0; i < 4; ++i)
                    #pragma unroll
                    for (int j = 0; j < 10; j += 2)
                        *(float2*)&Hbuf[tr * 4 + i][tc * 10 + j] =
                            make_float2(acc[i][j], acc[i][j + 1]);
                __syncthreads();
            }
        }
    }

    #pragma unroll
    for (int i = 0; i < 4; ++i) {
        const long e = base + tr * 4 + i;
        if (e >= E_EDGES) break;
        const int  de = dst[e];
        float* mp = Sout + (long)de * HD + tc * 10;
        #pragma unroll
        for (int j = 0; j < 10; ++j)
            unsafeAtomicAdd(mp + j, acc[i][j]);
    }
}

__global__ void k_mfix(float* __restrict__ Mg, const float* __restrict__ x)
{
    const int  lane = threadIdx.x & 63;
    const int  w    = threadIdx.x >> 6;
    const long n    = (long)blockIdx.x * 4 + w;
    if (n >= N_NODES) return;
    const long b = n * HD;
    float s = Mg[b + lane] + Mg[b + 64 + lane] + ((lane < 32) ? Mg[b + 128 + lane] : 0.f);
    #pragma unroll
    for (int off = 32; off > 0; off >>= 1) s += __shfl_xor(s, off, 64);
    if (s == 0.f) {
        Mg[b + lane]      = x[b + lane];
        Mg[b + 64 + lane] = x[b + 64 + lane];
        if (lane < 32) Mg[b + 128 + lane] = x[b + 128 + lane];
    }
}

// ---- k_out (both paths) ----
__global__ __launch_bounds__(256, 2)
void k_out(const float* __restrict__ x, const float* __restrict__ Mg,
           const float* __restrict__ Wo, const float* __restrict__ bo,
           float* __restrict__ out)
{
    __shared__ float At[KC][TE + 4];
    __shared__ float Wt[KC][HD + 8];

    const int  t    = threadIdx.x;
    const long base = (long)blockIdx.x * TE;
    const int  se  = t >> 2;
    const int  skq = t & 3;
    const long gn  = base + se;
    const bool ev  = gn < N_NODES;
    const long gnc = ev ? gn : 0;
    const float* xrow = x  + gnc * HD;
    const float* mrow = Mg + gnc * HD;
    const int tr = t >> 4, tc = t & 15;

    float acc[4][10];
    #pragma unroll
    for (int i = 0; i < 4; ++i)
        #pragma unroll
        for (int j = 0; j < 10; ++j) acc[i][j] = 0.f;

    for (int c = 0; c < KO / KC; ++c) {
        const int k0 = c * KC;
        __syncthreads();
        {
            const int kb = k0 + skq * 4;
            const float4 v = (kb < HD) ? *(const float4*)(xrow + kb)
                                       : *(const float4*)(mrow + (kb - HD));
            At[skq * 4 + 0][se] = v.x;
            At[skq * 4 + 1][se] = v.y;
            At[skq * 4 + 2][se] = v.z;
            At[skq * 4 + 3][se] = v.w;
        }
        for (int i = t; i < HD * KC; i += 256) {
            const int kk = i & (KC - 1);
            const int h  = i >> 4;
            Wt[kk][h] = Wo[h * KO + k0 + kk];
        }
        __syncthreads();
        gemm_chunk(acc, At, Wt, tr, tc);
    }
    #pragma unroll
    for (int i = 0; i < 4; ++i) {
        const long n = base + tr * 4 + i;
        if (n >= N_NODES) break;
        float* op = out + n * HD + tc * 10;
        #pragma unroll
        for (int j = 0; j < 10; j += 2) {
            float v0 = acc[i][j]     + bo[tc * 10 + j];
            float v1 = acc[i][j + 1] + bo[tc * 10 + j + 1];
            v0 = v0 > 0.f ? v0 : 0.f;
            v1 = v1 > 0.f ? v1 : 0.f;
            *(float2*)(op + j) = make_float2(v0, v1);
        }
    }
}

// ---------------------------------------------------------------------------
extern "C" void kernel_launch(void* const* d_in, const int* in_sizes, int n_in,
                              void* d_out, int out_size, void* d_ws, size_t ws_size,
                              hipStream_t stream)
{
    const float* x  = (const float*)d_in[0];
    const float* ea = (const float*)d_in[1];
    const int*   ei = (const int*)d_in[2];
    const float* Wi = (const float*)d_in[4];
    const float* bi = (const float*)d_in[5];
    const float* Wh = (const float*)d_in[6];
    const float* bh = (const float*)d_in[7];
    const float* Wo = (const float*)d_in[8];
    const float* bo = (const float*)d_in[9];
    float* out = (float*)d_out;

    const int* src = ei;
    const int* dst = ei + E_EDGES;

    const int gE = (E_EDGES + TE - 1) / TE;      // 7813
    const int gN = (N_NODES + TE - 1) / TE;      // 782
    const int gF = (N_NODES + 3) / 4;            // 12500
    const int gEe = (E_EDGES + 255) / 256;       // 1954

    // FAT layout (16B-aligned offsets):
    //   H0 @0 (320e6) | H @320e6 (320e6) | S @640e6 (32e6)
    //   ptr @672,000,000 (200,016 padded) | cnt @672,200,016 (200,000)
    //   cur @672,400,016 (200,000) | eid @672,600,016 (2,000,000)
    const size_t NEED_FAT = 675000000;

    if (ws_size >= NEED_FAT) {
        char* w = (char*)d_ws;
        float* H0  = (float*)(w);
        float* H   = (float*)(w + 320000000);
        float* S   = (float*)(w + 640000000);
        int*   ptr = (int*)  (w + 672000000);
        int*   cnt = (int*)  (w + 672200016);
        int*   cur = (int*)  (w + 672400016);
        int*   eid = (int*)  (w + 672600016);

        // zero cnt+cur (contiguous 400,000 B = 100,000 floats)
        k_zero<<<(100000 + 1023) / 1024, 256, 0, stream>>>((float*)cnt, 100000);
        k_csr_count<<<gEe, 256, 0, stream>>>(dst, cnt);
        k_csr_scan<<<1, 1024, 0, stream>>>(cnt, ptr);
        k_csr_fill<<<gEe, 256, 0, stream>>>(dst, ptr, cur, eid);

        k_h0f<<<gE, 256, 0, stream>>>(x, ea, src, Wi, bi, H0, H);
        k_seg<false><<<gF, 256, 0, stream>>>(H, ptr, eid, x, S);      // S0
        k_updf<<<gE, 256, 0, stream>>>(S, H0, src, Wh, bh, H);        // H1
        k_seg<false><<<gF, 256, 0, stream>>>(H, ptr, eid, x, S);      // S1
        k_updf<<<gE, 256, 0, stream>>>(S, H0, src, Wh, bh, H);        // H2
        k_seg<true ><<<gF, 256, 0, stream>>>(H, ptr, eid, x, S);      // M (+fix)
        k_out<<<gN, 256, 0, stream>>>(x, S, Wo, bo, out);
    } else {
        // SLIM: R4 structure, occupancy restored to 2 blocks/CU everywhere.
        const long NM = (long)N_NODES * HD;
        float* S0 = (float*)d_ws;
        float* S2 = S0 + NM;
        float* S1 = out;
        const int gZ2 = (int)((2 * NM + 1023) / 1024);
        const int gZ1 = (int)((NM + 1023) / 1024);

        k_zero<<<gZ2, 256, 0, stream>>>(S0, 2 * NM);
        k_zero<<<gZ1, 256, 0, stream>>>(S1, NM);

        k_mp<1><<<gE, 256, 0, stream>>>(x, ea, src, dst, Wi, bi, Wh, bh, x, x, S0);
        k_mp<2><<<gE, 256, 0, stream>>>(x, ea, src, dst, Wi, bi, Wh, bh, S0, S0, S1);
        k_mp<3><<<gE, 256, 0, stream>>>(x, ea, src, dst, Wi, bi, Wh, bh, S0, S1, S2);

        k_mfix<<<gF, 256, 0, stream>>>(S2, x);
        k_out<<<gN, 256, 0, stream>>>(x, S2, Wo, bo, out);
    }
}

// Round 6
// 3584.309 us; speedup vs baseline: 2.9587x; 2.5457x over previous
//
#include <hip/hip_runtime.h>

// Chemprop BondMessagePassing, DEPTH=3, eval mode.
// R5 decomposition: GEMM ~0.03ms/chunk (~85TF burst), atomic scatter ~2.2ms
// per k_mp (80M uncoalesced fp32 atomics) -> ~6.6ms of 9.1ms total.
// R6: (a) BF16-H CSR-gather path (195MB ws): zero atomics, H stored bf16,
//     segment-sum as per-node gather; update recomputes H0 and reads H[rev]
//     from global (per-wave in-place safe: wave touches only its own 16 rows).
// (b) slim fallback: coalesced atomic epilogue via Hbuf transpose
//     (64-consecutive-dword atomic instructions instead of 40B-strided).

#define E_EDGES 500000
#define N_NODES 50000
#define HD      160
#define BD      14
#define K1      174
#define K1P     176
#define KO      320

#define TE 64
#define KC 16
#define NC1 (K1P / KC)  // 11
#define NC2 (HD / KC)   // 10

// ---- bf16 helpers (values are relu outputs or finite; RNE rounding) ----
__device__ __forceinline__ unsigned short f2b(float v) {
    unsigned u = __float_as_uint(v);
    u += 0x7FFFu + ((u >> 16) & 1u);
    return (unsigned short)(u >> 16);
}
__device__ __forceinline__ float b2f(unsigned short h) {
    return __uint_as_float(((unsigned)h) << 16);
}

// ---------------------------------------------------------------------------
__global__ void k_zero(float* __restrict__ p, long n)
{
    const long i = (long)blockIdx.x * 1024 + (long)threadIdx.x * 4;
    if (i + 3 < n) *(float4*)(p + i) = make_float4(0.f, 0.f, 0.f, 0.f);
}

// ---------------------------------------------------------------------------
__device__ __forceinline__
void gemm_chunk(float acc[4][10], const float At[KC][TE + 4],
                const float Wt[KC][HD + 8], int tr, int tc)
{
    #pragma unroll
    for (int k = 0; k < KC; ++k) {
        const float4 a  = *(const float4*)&At[k][tr * 4];
        const float* wp = &Wt[k][tc * 10];
        float w[10];
        #pragma unroll
        for (int j = 0; j < 10; j += 2) {
            const float2 w2 = *(const float2*)(wp + j);
            w[j] = w2.x; w[j + 1] = w2.y;
        }
        #pragma unroll
        for (int j = 0; j < 10; ++j) {
            acc[0][j] = fmaf(a.x, w[j], acc[0][j]);
            acc[1][j] = fmaf(a.y, w[j], acc[1][j]);
            acc[2][j] = fmaf(a.z, w[j], acc[2][j]);
            acc[3][j] = fmaf(a.w, w[j], acc[3][j]);
        }
    }
}

// ============================ CSR build ====================================
__global__ void k_csr_count(const int* __restrict__ dst, int* __restrict__ cnt)
{
    const int e = blockIdx.x * 256 + threadIdx.x;
    if (e < E_EDGES) atomicAdd(&cnt[dst[e]], 1);
}

#define BPT 49
__global__ __launch_bounds__(1024)
void k_csr_scan(const int* __restrict__ cnt, int* __restrict__ ptr)
{
    __shared__ int part[1024];
    const int t  = threadIdx.x;
    const int lo = t * BPT;
    const int hi = min(lo + BPT, N_NODES);
    int s = 0;
    for (int i = lo; i < hi; ++i) s += cnt[i];
    part[t] = s;
    __syncthreads();
    for (int off = 1; off < 1024; off <<= 1) {
        int v = 0;
        if (t >= off) v = part[t - off];
        __syncthreads();
        if (t >= off) part[t] += v;
        __syncthreads();
    }
    int run = (t == 0) ? 0 : part[t - 1];
    for (int i = lo; i < hi; ++i) { ptr[i] = run; run += cnt[i]; }
    if (t == 1023) ptr[N_NODES] = part[1023];
}

__global__ void k_csr_fill(const int* __restrict__ dst, const int* __restrict__ ptr,
                           int* __restrict__ cur, int* __restrict__ eid)
{
    const int e = blockIdx.x * 256 + threadIdx.x;
    if (e < E_EDGES) {
        const int d   = dst[e];
        const int pos = atomicAdd(&cur[d], 1);
        eid[ptr[d] + pos] = e;
    }
}

// ============================ BF16 PATH ====================================

// ---- k_h0b: Hb[e] = bf16(relu(Wi @ [x[src]; ea] + bi)). Sequential writes.
__global__ __launch_bounds__(256, 3)
void k_h0b(const float* __restrict__ x, const float* __restrict__ ea,
           const int* __restrict__ src,
           const float* __restrict__ Wi, const float* __restrict__ bi,
           unsigned short* __restrict__ Hb)
{
    __shared__ float At[2][KC][TE + 4];
    __shared__ float Wt[2][KC][HD + 8];

    const int  t    = threadIdx.x;
    const long base = (long)blockIdx.x * TE;
    const int  se   = t >> 2;
    const int  skq  = t & 3;
    const long ge   = base + se;
    const bool ev   = ge < E_EDGES;
    const long gec  = ev ? ge : 0;
    const int  sidx = ev ? src[ge] : 0;
    const float* xrow = x  + (long)sidx * HD;
    const float* erow = ea + gec * BD;
    const int wk = t & 15, wh0 = t >> 4;
    const int tr = t >> 4, tc = t & 15;

    float4 pa; float pw[10];
    float acc[4][10];
    #pragma unroll
    for (int i = 0; i < 4; ++i)
        #pragma unroll
        for (int j = 0; j < 10; ++j) acc[i][j] = 0.f;

    auto pf_a = [&](int c) {
        const int kb = c * KC + skq * 4;
        if (kb + 3 < HD) pa = *(const float4*)(xrow + kb);
        else {
            float tmp[4];
            #pragma unroll
            for (int j = 0; j < 4; ++j) {
                const int k = kb + j;
                tmp[j] = (k < HD) ? xrow[k] : ((k < K1) ? erow[k - HD] : 0.f);
            }
            pa = make_float4(tmp[0], tmp[1], tmp[2], tmp[3]);
        }
    };
    auto pf_w = [&](int c) {
        const int k = c * KC + wk;
        #pragma unroll
        for (int m = 0; m < 10; ++m)
            pw[m] = (k < K1) ? Wi[(wh0 + 16 * m) * K1 + k] : 0.f;
    };

    pf_a(0); pf_w(0);
    for (int c = 0; c < NC1; ++c) {
        const int buf = c & 1;
        At[buf][skq * 4 + 0][se] = pa.x;
        At[buf][skq * 4 + 1][se] = pa.y;
        At[buf][skq * 4 + 2][se] = pa.z;
        At[buf][skq * 4 + 3][se] = pa.w;
        #pragma unroll
        for (int m = 0; m < 10; ++m) Wt[buf][wk][wh0 + 16 * m] = pw[m];
        __syncthreads();
        if (c + 1 < NC1) { pf_a(c + 1); pf_w(c + 1); }
        gemm_chunk(acc, At[buf], Wt[buf], tr, tc);
    }
    #pragma unroll
    for (int i = 0; i < 4; ++i) {
        const long e = base + tr * 4 + i;
        if (e >= E_EDGES) break;
        unsigned short* hp = Hb + e * HD + tc * 10;
        #pragma unroll
        for (int j = 0; j < 10; j += 2) {
            float v0 = acc[i][j]     + bi[tc * 10 + j];
            float v1 = acc[i][j + 1] + bi[tc * 10 + j + 1];
            v0 = v0 > 0.f ? v0 : 0.f;
            v1 = v1 > 0.f ? v1 : 0.f;
            *(ushort2*)(hp + j) = make_ushort2(f2b(v0), f2b(v1));
        }
    }
}

// ---- k_segb<FINAL>: S[n] = sum_{e in in(n)} Hb[e]; gather, zero atomics. --
template <bool FINAL>
__global__ void k_segb(const unsigned short* __restrict__ Hb,
                       const int* __restrict__ ptr, const int* __restrict__ eid,
                       const float* __restrict__ x, float* __restrict__ S)
{
    const int  lane = threadIdx.x & 63;
    const int  w    = threadIdx.x >> 6;
    const long n    = (long)blockIdx.x * 4 + w;
    if (n >= N_NODES) return;
    const int p0 = ptr[n], p1 = ptr[n + 1];
    float a0 = 0.f, a1 = 0.f, a2 = 0.f;
    for (int i = p0; i < p1; ++i) {
        const unsigned short* row = Hb + (long)eid[i] * HD;
        a0 += b2f(row[lane]);
        a1 += b2f(row[64 + lane]);
        if (lane < 32) a2 += b2f(row[128 + lane]);
    }
    const long sb = n * HD;
    if (FINAL) {
        float s = a0 + a1 + a2;
        #pragma unroll
        for (int off = 32; off > 0; off >>= 1) s += __shfl_xor(s, off, 64);
        if (s == 0.f) {
            S[sb + lane]      = x[sb + lane];
            S[sb + 64 + lane] = x[sb + 64 + lane];
            if (lane < 32) S[sb + 128 + lane] = x[sb + 128 + lane];
            return;
        }
    }
    S[sb + lane]      = a0;
    S[sb + 64 + lane] = a1;
    if (lane < 32) S[sb + 128 + lane] = a2;
}

// ---- k_updb: Hb[e] = bf16(relu(H0[e] + Wh @ (S[src[e]] - Hb[e^1]) + bh)),
// H0 recomputed in-kernel (phase 1). In-place safe per wave: each wave only
// reads/writes rows [16w,16w+16) of its tile, and all its loads are consumed
// by FMAs before its epilogue stores issue. ----
__global__ __launch_bounds__(256, 3)
void k_updb(const float* __restrict__ S,
            const float* __restrict__ x, const float* __restrict__ ea,
            const int* __restrict__ src,
            const float* __restrict__ Wi, const float* __restrict__ bi,
            const float* __restrict__ Wh, const float* __restrict__ bh,
            unsigned short* __restrict__ Hb)
{
    __shared__ float At[2][KC][TE + 4];
    __shared__ float Wt[2][KC][HD + 8];

    const int  t    = threadIdx.x;
    const long base = (long)blockIdx.x * TE;
    const int  se   = t >> 2;
    const int  skq  = t & 3;
    const long ge   = base + se;
    const bool ev   = ge < E_EDGES;
    const long gec  = ev ? ge : 0;
    const int  sidx = ev ? src[ge] : 0;
    const float* xrow = x  + (long)sidx * HD;
    const float* erow = ea + gec * BD;
    const float* mrow = S  + (long)sidx * HD;
    const unsigned short* rrow = Hb + (gec ^ 1) * HD;
    const int wk = t & 15, wh0 = t >> 4;
    const int tr = t >> 4, tc = t & 15;

    float4 pa; ushort4 pr; float pw[10];
    float acc[4][10];
    #pragma unroll
    for (int i = 0; i < 4; ++i)
        #pragma unroll
        for (int j = 0; j < 10; ++j) acc[i][j] = 0.f;

    auto pf_a1 = [&](int c) {
        const int kb = c * KC + skq * 4;
        if (kb + 3 < HD) pa = *(const float4*)(xrow + kb);
        else {
            float tmp[4];
            #pragma unroll
            for (int j = 0; j < 4; ++j) {
                const int k = kb + j;
                tmp[j] = (k < HD) ? xrow[k] : ((k < K1) ? erow[k - HD] : 0.f);
            }
            pa = make_float4(tmp[0], tmp[1], tmp[2], tmp[3]);
        }
    };
    auto pf_wi = [&](int c) {
        const int k = c * KC + wk;
        #pragma unroll
        for (int m = 0; m < 10; ++m)
            pw[m] = (k < K1) ? Wi[(wh0 + 16 * m) * K1 + k] : 0.f;
    };
    auto pf_wh = [&](int c) {
        const int k = c * KC + wk;
        #pragma unroll
        for (int m = 0; m < 10; ++m) pw[m] = Wh[(wh0 + 16 * m) * HD + k];
    };

    // ---- phase 1: acc = [x[src]; ea] @ Wi^T ----
    pf_a1(0); pf_wi(0);
    for (int c = 0; c < NC1; ++c) {
        const int buf = c & 1;
        At[buf][skq * 4 + 0][se] = pa.x;
        At[buf][skq * 4 + 1][se] = pa.y;
        At[buf][skq * 4 + 2][se] = pa.z;
        At[buf][skq * 4 + 3][se] = pa.w;
        #pragma unroll
        for (int m = 0; m < 10; ++m) Wt[buf][wk][wh0 + 16 * m] = pw[m];
        __syncthreads();
        if (c + 1 < NC1) { pf_a1(c + 1); pf_wi(c + 1); }
        gemm_chunk(acc, At[buf], Wt[buf], tr, tc);
    }
    // H0 = relu(acc + bi), keep in h0r; reset acc
    float h0r[4][10];
    #pragma unroll
    for (int j = 0; j < 10; ++j) {
        const float b = bi[tc * 10 + j];
        #pragma unroll
        for (int i = 0; i < 4; ++i) {
            const float v = acc[i][j] + b;
            h0r[i][j] = v > 0.f ? v : 0.f;
            acc[i][j] = 0.f;
        }
    }

    // ---- phase 2: acc = (S[src] - Hb[e^1]) @ Wh^T ----
    __syncthreads();   // separate phase-1 buf readers from phase-2 writers
    pa = *(const float4*)(mrow + skq * 4);
    pr = *(const ushort4*)(rrow + skq * 4);
    pf_wh(0);
    for (int c = 0; c < NC2; ++c) {
        const int buf = c & 1;
        At[buf][skq * 4 + 0][se] = pa.x - b2f(pr.x);
        At[buf][skq * 4 + 1][se] = pa.y - b2f(pr.y);
        At[buf][skq * 4 + 2][se] = pa.z - b2f(pr.z);
        At[buf][skq * 4 + 3][se] = pa.w - b2f(pr.w);
        #pragma unroll
        for (int m = 0; m < 10; ++m) Wt[buf][wk][wh0 + 16 * m] = pw[m];
        __syncthreads();
        if (c + 1 < NC2) {
            const int kb = (c + 1) * KC + skq * 4;
            pa = *(const float4*)(mrow + kb);
            pr = *(const ushort4*)(rrow + kb);
            pf_wh(c + 1);
        }
        gemm_chunk(acc, At[buf], Wt[buf], tr, tc);
    }

    // ---- epilogue: Hb[e] = bf16(relu(H0 + acc + bh)) ----
    #pragma unroll
    for (int i = 0; i < 4; ++i) {
        const long e = base + tr * 4 + i;
        if (e >= E_EDGES) break;
        unsigned short* hp = Hb + e * HD + tc * 10;
        #pragma unroll
        for (int j = 0; j < 10; j += 2) {
            float v0 = h0r[i][j]     + acc[i][j]     + bh[tc * 10 + j];
            float v1 = h0r[i][j + 1] + acc[i][j + 1] + bh[tc * 10 + j + 1];
            v0 = v0 > 0.f ? v0 : 0.f;
            v1 = v1 > 0.f ? v1 : 0.f;
            *(ushort2*)(hp + j) = make_ushort2(f2b(v0), f2b(v1));
        }
    }
}

// ============================ SLIM PATH ====================================

template <int LAYERS>
__global__ __launch_bounds__(256, 2)
void k_mp(const float* __restrict__ x, const float* __restrict__ ea,
          const int* __restrict__ src, const int* __restrict__ dst,
          const float* __restrict__ Wi, const float* __restrict__ bi,
          const float* __restrict__ Wh, const float* __restrict__ bh,
          const float* __restrict__ S0, const float* __restrict__ S1,
          float* __restrict__ Sout)
{
    __shared__ float At[2][KC][TE + 4];
    __shared__ float Wt[2][KC][HD + 8];
    __shared__ float Hbuf[TE][HD + 4];   // layer exchange + epilogue transpose

    const int  t    = threadIdx.x;
    const long base = (long)blockIdx.x * TE;
    const int  se   = t >> 2;
    const int  skq  = t & 3;
    const long ge   = base + se;
    const bool ev   = ge < E_EDGES;
    const long gec  = ev ? ge : 0;
    const int  sidx = ev ? src[ge] : 0;
    const float* xrow = x  + (long)sidx * HD;
    const float* erow = ea + gec * BD;
    const int wk = t & 15, wh0 = t >> 4;
    const int tr = t >> 4, tc = t & 15;

    float4 pa; float pw[10];
    float acc[4][10];
    #pragma unroll
    for (int i = 0; i < 4; ++i)
        #pragma unroll
        for (int j = 0; j < 10; ++j) acc[i][j] = 0.f;

    auto pf_a1 = [&](int c) {
        const int kb = c * KC + skq * 4;
        if (kb + 3 < HD) pa = *(const float4*)(xrow + kb);
        else {
            float tmp[4];
            #pragma unroll
            for (int j = 0; j < 4; ++j) {
                const int k = kb + j;
                tmp[j] = (k < HD) ? xrow[k] : ((k < K1) ? erow[k - HD] : 0.f);
            }
            pa = make_float4(tmp[0], tmp[1], tmp[2], tmp[3]);
        }
    };
    auto pf_w = [&](const float* __restrict__ W, int ld, int kmax, int c) {
        const int k = c * KC + wk;
        #pragma unroll
        for (int m = 0; m < 10; ++m)
            pw[m] = (k < kmax) ? W[(wh0 + 16 * m) * ld + k] : 0.f;
    };

    pf_a1(0); pf_w(Wi, K1, K1, 0);
    for (int c = 0; c < NC1; ++c) {
        const int buf = c & 1;
        At[buf][skq * 4 + 0][se] = pa.x;
        At[buf][skq * 4 + 1][se] = pa.y;
        At[buf][skq * 4 + 2][se] = pa.z;
        At[buf][skq * 4 + 3][se] = pa.w;
        #pragma unroll
        for (int m = 0; m < 10; ++m) Wt[buf][wk][wh0 + 16 * m] = pw[m];
        __syncthreads();
        if (c + 1 < NC1) { pf_a1(c + 1); pf_w(Wi, K1, K1, c + 1); }
        gemm_chunk(acc, At[buf], Wt[buf], tr, tc);
    }
    #pragma unroll
    for (int j = 0; j < 10; ++j) {
        const float b = bi[tc * 10 + j];
        #pragma unroll
        for (int i = 0; i < 4; ++i) {
            const float v = acc[i][j] + b;
            acc[i][j] = v > 0.f ? v : 0.f;
        }
    }

    float h0r[4][10];
    if (LAYERS >= 2) {
        #pragma unroll
        for (int i = 0; i < 4; ++i)
            #pragma unroll
            for (int j = 0; j < 10; ++j) h0r[i][j] = acc[i][j];
        #pragma unroll
        for (int i = 0; i < 4; ++i)
            #pragma unroll
            for (int j = 0; j < 10; j += 2)
                *(float2*)&Hbuf[tr * 4 + i][tc * 10 + j] =
                    make_float2(acc[i][j], acc[i][j + 1]);
        __syncthreads();

        #pragma unroll
        for (int l = 1; l < LAYERS; ++l) {
            const float* Sp   = (l == 1) ? S0 : S1;
            const float* mrow = Sp + (long)sidx * HD;
            #pragma unroll
            for (int i = 0; i < 4; ++i)
                #pragma unroll
                for (int j = 0; j < 10; ++j) acc[i][j] = 0.f;

            pa = *(const float4*)(mrow + skq * 4);
            pf_w(Wh, HD, HD, 0);
            for (int c = 0; c < NC2; ++c) {
                const int buf = c & 1;
                const int kb  = c * KC + skq * 4;
                {
                    const float4 r = *(const float4*)&Hbuf[se ^ 1][kb];
                    At[buf][skq * 4 + 0][se] = pa.x - r.x;
                    At[buf][skq * 4 + 1][se] = pa.y - r.y;
                    At[buf][skq * 4 + 2][se] = pa.z - r.z;
                    At[buf][skq * 4 + 3][se] = pa.w - r.w;
                }
                #pragma unroll
                for (int m = 0; m < 10; ++m) Wt[buf][wk][wh0 + 16 * m] = pw[m];
                __syncthreads();
                if (c + 1 < NC2) {
                    pa = *(const float4*)(mrow + (c + 1) * KC + skq * 4);
                    pf_w(Wh, HD, HD, c + 1);
                }
                gemm_chunk(acc, At[buf], Wt[buf], tr, tc);
            }
            #pragma unroll
            for (int j = 0; j < 10; ++j) {
                const float b = bh[tc * 10 + j];
                #pragma unroll
                for (int i = 0; i < 4; ++i) {
                    const float v = h0r[i][j] + acc[i][j] + b;
                    acc[i][j] = v > 0.f ? v : 0.f;
                }
            }
            if (l < LAYERS - 1) {
                #pragma unroll
                for (int i = 0; i < 4; ++i)
                    #pragma unroll
                    for (int j = 0; j < 10; j += 2)
                        *(float2*)&Hbuf[tr * 4 + i][tc * 10 + j] =
                            make_float2(acc[i][j], acc[i][j + 1]);
                __syncthreads();
            }
        }
    }

    // ---- coalesced scatter epilogue: acc -> Hbuf -> contiguous atomics ----
    #pragma unroll
    for (int i = 0; i < 4; ++i)
        #pragma unroll
        for (int j = 0; j < 10; j += 2)
            *(float2*)&Hbuf[tr * 4 + i][tc * 10 + j] =
                make_float2(acc[i][j], acc[i][j + 1]);
    __syncthreads();
    const int lane = t & 63;
    const int wv   = t >> 6;
    for (int r = 0; r < 16; ++r) {
        const int  row = wv * 16 + r;
        const long e   = base + row;
        if (e >= E_EDGES) break;
        const int d = dst[e];
        float* mp = Sout + (long)d * HD;
        unsafeAtomicAdd(mp + lane,      Hbuf[row][lane]);
        unsafeAtomicAdd(mp + 64 + lane, Hbuf[row][64 + lane]);
        if (lane < 32) unsafeAtomicAdd(mp + 128 + lane, Hbuf[row][128 + lane]);
    }
}

__global__ void k_mfix(float* __restrict__ Mg, const float* __restrict__ x)
{
    const int  lane = threadIdx.x & 63;
    const int  w    = threadIdx.x >> 6;
    const long n    = (long)blockIdx.x * 4 + w;
    if (n >= N_NODES) return;
    const long b = n * HD;
    float s = Mg[b + lane] + Mg[b + 64 + lane] + ((lane < 32) ? Mg[b + 128 + lane] : 0.f);
    #pragma unroll
    for (int off = 32; off > 0; off >>= 1) s += __shfl_xor(s, off, 64);
    if (s == 0.f) {
        Mg[b + lane]      = x[b + lane];
        Mg[b + 64 + lane] = x[b + 64 + lane];
        if (lane < 32) Mg[b + 128 + lane] = x[b + 128 + lane];
    }
}

// ---- k_out (both paths) ----
__global__ __launch_bounds__(256, 2)
void k_out(const float* __restrict__ x, const float* __restrict__ Mg,
           const float* __restrict__ Wo, const float* __restrict__ bo,
           float* __restrict__ out)
{
    __shared__ float At[KC][TE + 4];
    __shared__ float Wt[KC][HD + 8];

    const int  t    = threadIdx.x;
    const long base = (long)blockIdx.x * TE;
    const int  se  = t >> 2;
    const int  skq = t & 3;
    const long gn  = base + se;
    const bool ev  = gn < N_NODES;
    const long gnc = ev ? gn : 0;
    const float* xrow = x  + gnc * HD;
    const float* mrow = Mg + gnc * HD;
    const int tr = t >> 4, tc = t & 15;

    float acc[4][10];
    #pragma unroll
    for (int i = 0; i < 4; ++i)
        #pragma unroll
        for (int j = 0; j < 10; ++j) acc[i][j] = 0.f;

    for (int c = 0; c < KO / KC; ++c) {
        const int k0 = c * KC;
        __syncthreads();
        {
            const int kb = k0 + skq * 4;
            const float4 v = (kb < HD) ? *(const float4*)(xrow + kb)
                                       : *(const float4*)(mrow + (kb - HD));
            At[skq * 4 + 0][se] = v.x;
            At[skq * 4 + 1][se] = v.y;
            At[skq * 4 + 2][se] = v.z;
            At[skq * 4 + 3][se] = v.w;
        }
        for (int i = t; i < HD * KC; i += 256) {
            const int kk = i & (KC - 1);
            const int h  = i >> 4;
            Wt[kk][h] = Wo[h * KO + k0 + kk];
        }
        __syncthreads();
        gemm_chunk(acc, At, Wt, tr, tc);
    }
    #pragma unroll
    for (int i = 0; i < 4; ++i) {
        const long n = base + tr * 4 + i;
        if (n >= N_NODES) break;
        float* op = out + n * HD + tc * 10;
        #pragma unroll
        for (int j = 0; j < 10; j += 2) {
            float v0 = acc[i][j]     + bo[tc * 10 + j];
            float v1 = acc[i][j + 1] + bo[tc * 10 + j + 1];
            v0 = v0 > 0.f ? v0 : 0.f;
            v1 = v1 > 0.f ? v1 : 0.f;
            *(float2*)(op + j) = make_float2(v0, v1);
        }
    }
}

// ---------------------------------------------------------------------------
extern "C" void kernel_launch(void* const* d_in, const int* in_sizes, int n_in,
                              void* d_out, int out_size, void* d_ws, size_t ws_size,
                              hipStream_t stream)
{
    const float* x  = (const float*)d_in[0];
    const float* ea = (const float*)d_in[1];
    const int*   ei = (const int*)d_in[2];
    const float* Wi = (const float*)d_in[4];
    const float* bi = (const float*)d_in[5];
    const float* Wh = (const float*)d_in[6];
    const float* bh = (const float*)d_in[7];
    const float* Wo = (const float*)d_in[8];
    const float* bo = (const float*)d_in[9];
    float* out = (float*)d_out;

    const int* src = ei;
    const int* dst = ei + E_EDGES;

    const int gE  = (E_EDGES + TE - 1) / TE;     // 7813
    const int gN  = (N_NODES + TE - 1) / TE;     // 782
    const int gF  = (N_NODES + 3) / 4;           // 12500
    const int gEe = (E_EDGES + 255) / 256;       // 1954

    // BF16 layout: Hb @0 (160e6) | S @160e6 (32e6) | ptr @192e6 (200,016)
    //   cnt @192,200,016 (200,000) | cur @192,400,016 (200,000)
    //   eid @192,600,016 (2e6) -> end 194,600,016
    const size_t NEED_BF = 195000000;

    if (ws_size >= NEED_BF) {
        char* w = (char*)d_ws;
        unsigned short* Hb = (unsigned short*)(w);
        float* S   = (float*)(w + 160000000);
        int*   ptr = (int*)  (w + 192000000);
        int*   cnt = (int*)  (w + 192200016);
        int*   cur = (int*)  (w + 192400016);
        int*   eid = (int*)  (w + 192600016);
        float* S1  = out;   // d_out doubles as middle segment-sum buffer

        k_zero<<<(100000 + 1023) / 1024, 256, 0, stream>>>((float*)cnt, 100000);
        k_csr_count<<<gEe, 256, 0, stream>>>(dst, cnt);
        k_csr_scan<<<1, 1024, 0, stream>>>(cnt, ptr);
        k_csr_fill<<<gEe, 256, 0, stream>>>(dst, ptr, cur, eid);

        k_h0b<<<gE, 256, 0, stream>>>(x, ea, src, Wi, bi, Hb);
        k_segb<false><<<gF, 256, 0, stream>>>(Hb, ptr, eid, x, S);     // S0
        k_updb<<<gE, 256, 0, stream>>>(S, x, ea, src, Wi, bi, Wh, bh, Hb);
        k_segb<false><<<gF, 256, 0, stream>>>(Hb, ptr, eid, x, S1);    // S1
        k_updb<<<gE, 256, 0, stream>>>(S1, x, ea, src, Wi, bi, Wh, bh, Hb);
        k_segb<true ><<<gF, 256, 0, stream>>>(Hb, ptr, eid, x, S);     // M (+fix)
        k_out<<<gN, 256, 0, stream>>>(x, S, Wo, bo, out);
    } else {
        // SLIM: 64 MB ws; coalesced-atomic epilogue.
        const long NM = (long)N_NODES * HD;
        float* S0 = (float*)d_ws;
        float* S2 = S0 + NM;
        float* S1 = out;
        const int gZ2 = (int)((2 * NM + 1023) / 1024);
        const int gZ1 = (int)((NM + 1023) / 1024);

        k_zero<<<gZ2, 256, 0, stream>>>(S0, 2 * NM);
        k_zero<<<gZ1, 256, 0, stream>>>(S1, NM);

        k_mp<1><<<gE, 256, 0, stream>>>(x, ea, src, dst, Wi, bi, Wh, bh, x, x, S0);
        k_mp<2><<<gE, 256, 0, stream>>>(x, ea, src, dst, Wi, bi, Wh, bh, S0, S0, S1);
        k_mp<3><<<gE, 256, 0, stream>>>(x, ea, src, dst, Wi, bi, Wh, bh, S0, S1, S2);

        k_mfix<<<gF, 256, 0, stream>>>(S2, x);
        k_out<<<gN, 256, 0, stream>>>(x, S2, Wo, bo, out);
    }
}